// Round 9
// baseline (57.777 us; speedup 1.0000x reference)
//
#include <hip/hip_runtime.h>

#define B_ 4
#define R_ 48
#define VR_ 96
#define NBLK (B_ * R_ * 12)     // 2304 blocks: (b, r, quad); 4 waves = 4 s-cells
#define NGRP 36                 // completion tree: 2304/64 blocks per group
#define SLOTS_PER_B 16          // psum slots per batch, one cache line each

typedef float v2f __attribute__((ext_vector_type(2)));
struct F3 { float x, y, z; };   // 12B, 4B-aligned -> dwordx3 load

// ws control block (zeroed by memset node every launch):
// [0,    4096): psum  — 64 slots x 16 floats (one 64B line per slot)
// [4096, 6400): gc    — 36 counters x 16 uints (one line each)
// [6400, 6404): master counter (64B-aligned line)

// ---------------------------------------------------------------------------
// Detect cmaps element width from its first 256 bytes (wave-local ballot,
// no barrier). int32 layout: bytes at i%4!=0 all zero; f32 layout: contains
// 0x80/0x3F exponent bytes; bool layout: random 0/1 bytes, some nonzero,
// none > 1. Deterministic for fixed inputs.
__device__ __forceinline__ int detect_stride4(const unsigned char* cm, int lane) {
  const unsigned int d = ((const unsigned int*)cm)[lane];
  const unsigned int b1 = (d >> 8) & 0xff, b2 = (d >> 16) & 0xff, b3 = d >> 24;
  const unsigned long long nzm = __ballot((b1 | b2 | b3) != 0);
  const unsigned long long bigm = __ballot((b1 > 1) || (b2 > 1) || (b3 > 1));
  return (bigm != 0ull || nzm == 0ull) ? 1 : 0;
}

// ---------------------------------------------------------------------------
// Single fused kernel: gather + per-cell min + distributed masked-mean.
// One wave per (b,r,s) cell, 4 cells/block sharing the g1 row. Block partial
// goes to a padded psum slot (36-deep chains, 64 parallel lines). Tree-
// structured completion (36 group counters -> 1 master, max chain 64) elects
// ONE finalizer block; all cross-block dataflow is atomic-RMW only.
__global__ __launch_bounds__(256) void fused_all_kernel(
    const float* __restrict__ v1s, const float* __restrict__ v2s,
    const int* __restrict__ rid_to_vid, const unsigned char* __restrict__ cm,
    float* __restrict__ ctrl, float* __restrict__ out, int N) {
  const int bid = blockIdx.x;              // b*(48*12) + r*12 + quad
  const int b = bid / (R_ * 12);
  const int rem = bid % (R_ * 12);
  const int r = rem / 12;
  const int quad = rem % 12;
  const int t = threadIdx.x;
  const int w = t >> 6, lane = t & 63;
  const int s = quad * 4 + w;
  const int cellIdx = (b * R_ + r) * R_ + s;
  const size_t bN3 = (size_t)b * N * 3;

  float* const psum = ctrl;                                  // 64 x 16 floats
  unsigned* const gc = (unsigned*)(ctrl + 1024);             // 36 x 16 uints
  unsigned* const master = (unsigned*)(ctrl + 1600);         // 1 uint

  // ---- issue all gather loads first (no cmaps dependency) ----
  F3 pt1;
  const bool have1 = (t < VR_);
  if (have1) {
    const int idx = rid_to_vid[r * VR_ + t];
    pt1 = *(const F3*)(v1s + bN3 + (size_t)idx * 3);
  }
  const int row0 = t / VR_, v0 = t % VR_;
  const int idx0 = rid_to_vid[(quad * 4 + row0) * VR_ + v0];
  const F3 pt2a = *(const F3*)(v2s + bN3 + (size_t)idx0 * 3);
  const int p1 = t + 256;
  const bool have2b = (p1 < 4 * VR_);
  int row1 = 3, v1 = 0;
  F3 pt2b;
  if (have2b) {
    row1 = p1 / VR_; v1 = p1 % VR_;
    const int idx1 = rid_to_vid[(quad * 4 + row1) * VR_ + v1];
    pt2b = *(const F3*)(v2s + bN3 + (size_t)idx1 * 3);
  }

  // ---- overlap: mask layout detect + this wave's cell mask ----
  const int stride4 = detect_stride4(cm, lane);
  const unsigned int* cm32 = (const unsigned int*)cm;
  const bool active = stride4 ? (cm32[cellIdx] != 0u) : (cm[cellIdx] != 0);

  // ---- LDS SoA stores + single barrier ----
  __shared__ float s1[3 * VR_];
  __shared__ float s2[4][3 * VR_];
  if (have1) { s1[t] = pt1.x; s1[VR_ + t] = pt1.y; s1[2 * VR_ + t] = pt1.z; }
  s2[row0][v0] = pt2a.x; s2[row0][VR_ + v0] = pt2a.y; s2[row0][2 * VR_ + v0] = pt2a.z;
  if (have2b) { s2[row1][v1] = pt2b.x; s2[row1][VR_ + v1] = pt2b.y; s2[row1][2 * VR_ + v1] = pt2b.z; }
  __syncthreads();

  float mind = 0.0f;
  if (active) {                             // wave-uniform; inactive waves idle
    const float* r2 = s2[w];
    const int hi = lane >> 3, lo = lane & 7;  // 8x8 lane grid, 12x12 pair tile

    float Ax[12], Ay[12], Az[12];
    v2f Bx[6], By[6], Bz[6];
#pragma unroll
    for (int k = 0; k < 3; ++k) {
      *(float4*)&Ax[4 * k] = *(const float4*)(s1           + hi * 12 + 4 * k);
      *(float4*)&Ay[4 * k] = *(const float4*)(s1 +     VR_ + hi * 12 + 4 * k);
      *(float4*)&Az[4 * k] = *(const float4*)(s1 + 2 * VR_ + hi * 12 + 4 * k);
      *(float4*)&Bx[2 * k] = *(const float4*)(r2           + lo * 12 + 4 * k);
      *(float4*)&By[2 * k] = *(const float4*)(r2 +     VR_ + lo * 12 + 4 * k);
      *(float4*)&Bz[2 * k] = *(const float4*)(r2 + 2 * VR_ + lo * 12 + 4 * k);
    }

    float acc[4] = {3.4e38f, 3.4e38f, 3.4e38f, 3.4e38f};
#pragma unroll
    for (int i = 0; i < 12; ++i) {
      const v2f axx = {Ax[i], Ax[i]};
      const v2f ayy = {Ay[i], Ay[i]};
      const v2f azz = {Az[i], Az[i]};
#pragma unroll
      for (int j = 0; j < 6; ++j) {
        const v2f dx = axx - Bx[j];
        const v2f dy = ayy - By[j];
        const v2f dz = azz - Bz[j];
        const v2f d2 = dx * dx + dy * dy + dz * dz;
        acc[j & 3] = fminf(acc[j & 3], fminf(d2.x, d2.y));   // v_min3
      }
    }
    float mind2 = fminf(fminf(acc[0], acc[1]), fminf(acc[2], acc[3]));
#pragma unroll
    for (int off = 32; off > 0; off >>= 1)
      mind2 = fminf(mind2, __shfl_down(mind2, off, 64));
    mind = sqrtf(fmaxf(mind2, 0.0f));
  }

  // ---- block partial -> padded psum slot; completion tree ----
  __shared__ float sm[4];
  __shared__ int finflag;
  if (t == 0) finflag = 0;
  if (lane == 0) sm[w] = mind;              // inactive waves wrote 0
  __syncthreads();
  if (t == 0) {
    const float partial = sm[0] + sm[1] + sm[2] + sm[3];
    atomicAdd(&psum[(b * SLOTS_PER_B + (bid & (SLOTS_PER_B - 1))) * 16], partial);
    __threadfence();                        // release: psum-add before gc-add
    const unsigned old = atomicAdd(&gc[(bid >> 6) * 16], 1u);
    if (old == 63u) {                       // group complete
      const unsigned m = atomicAdd(master, 1u);
      if (m == NGRP - 1u) finflag = 1;      // all groups complete -> finalizer
    }
  }
  __syncthreads();
  if (!finflag) return;

  // ---- finalizer block (exactly one; all prior atomics complete) ----
  __threadfence();
  float slotv = 0.0f;
  if (t < 64) slotv = atomicAdd(&psum[t * 16], 0.0f);  // coherent read (old==sum)
#pragma unroll
  for (int off = 8; off > 0; off >>= 1)
    slotv += __shfl_down(slotv, off, 16);   // reduce within 16-slot batch groups
  __shared__ float bsum[4];
  if (t < 64 && (t & 15) == 0) bsum[t >> 4] = slotv;

  __shared__ float bcnt[4];
  __shared__ float wc[4];
  for (int bb = 0; bb < B_; ++bb) {
    float c = 0.0f;
    for (int i = t; i < R_ * R_; i += 256) {
      const int gi = bb * R_ * R_ + i;
      c += (stride4 ? (cm32[gi] != 0u) : (cm[gi] != 0)) ? 1.0f : 0.0f;
    }
#pragma unroll
    for (int off = 32; off > 0; off >>= 1) c += __shfl_down(c, off, 64);
    if ((t & 63) == 0) wc[t >> 6] = c;
    __syncthreads();
    if (t == 0) bcnt[bb] = wc[0] + wc[1] + wc[2] + wc[3];
    __syncthreads();
  }
  if (t < 4) out[t] = bsum[t] / bcnt[t];
}

// ---------------------------------------------------------------------------
extern "C" void kernel_launch(void* const* d_in, const int* in_sizes, int n_in,
                              void* d_out, int out_size, void* d_ws, size_t ws_size,
                              hipStream_t stream) {
  const float* v1s = (const float*)d_in[0];
  const float* v2s = (const float*)d_in[1];
  const unsigned char* cmaps = (const unsigned char*)d_in[2];
  const int* rid_to_vid = (const int*)d_in[3];
  float* out = (float*)d_out;
  float* ctrl = (float*)d_ws;

  const int N = in_sizes[0] / (B_ * 3);

  hipMemsetAsync(d_ws, 0, 8192, stream);   // zero psum/gc/master every launch
  fused_all_kernel<<<NBLK, 256, 0, stream>>>(
      v1s, v2s, rid_to_vid, cmaps, ctrl, out, N);
}

// Round 10
// 23.212 us; speedup vs baseline: 2.4891x; 2.4891x over previous
//
#include <hip/hip_runtime.h>

#define B_ 4
#define R_ 48
#define VR_ 96
#define NBLK (B_ * 24 * 12)     // 1152 blocks: (b, r-pair, s-quad); 8 waves = 2x4 cells

typedef float v2f __attribute__((ext_vector_type(2)));
struct F3 { float x, y, z; };   // 12B, 4B-aligned -> dwordx3 load

// ---------------------------------------------------------------------------
// Detect cmaps element width from its first 256 bytes (wave-local ballot, no
// barrier). int32 layout: bytes at i%4!=0 all zero; f32 layout: contains
// 0x80/0x3F exponent bytes; bool layout: random 0/1 bytes, some nonzero,
// none > 1. Deterministic for fixed inputs.
__device__ __forceinline__ int detect_stride4(const unsigned char* cm, int lane) {
  const unsigned int d = ((const unsigned int*)cm)[lane];
  const unsigned int b1 = (d >> 8) & 0xff, b2 = (d >> 16) & 0xff, b3 = d >> 24;
  const unsigned long long nzm = __ballot((b1 | b2 | b3) != 0);
  const unsigned long long bigm = __ballot((b1 > 1) || (b2 > 1) || (b3 > 1));
  return (bigm != 0ull || nzm == 0ull) ? 1 : 0;
}

// ---------------------------------------------------------------------------
// Kernel 1: fused gather + min-distance over a 2x4 cell tile. 8 waves/block,
// one wave per cell (same 9216-wave parallelism as the 4-wave version), but
// 6 gathered rows serve 8 cells -> scattered-load traffic ~halves. Gather
// loads issue FIRST (independent of cmaps) to overlap mask reads; single
// barrier; per-wave masked exit. Plain stores only — no atomics, no fences.
__global__ __launch_bounds__(512) void fused_cell_kernel(
    const float* __restrict__ v1s, const float* __restrict__ v2s,
    const int* __restrict__ rid_to_vid, const unsigned char* __restrict__ cm,
    float* __restrict__ minbuf, int N) {
  const int bid = blockIdx.x;              // b*288 + rp*12 + sq
  const int b = bid / 288;
  const int rem = bid % 288;
  const int rp = rem / 12;                 // r-pair: rows rp*2, rp*2+1
  const int sq = rem % 12;                 // s-quad: cols sq*4 .. sq*4+3
  const int t = threadIdx.x;
  const int w = t >> 6, lane = t & 63;
  const int r = rp * 2 + (w >> 2);
  const int s = sq * 4 + (w & 3);
  const int cellIdx = (b * R_ + r) * R_ + s;
  const size_t bN3 = (size_t)b * N * 3;

  // ---- issue all gather loads first (no cmaps dependency) ----
  // 6 rows x 96 = 576 points over 512 threads: p0 = t, p1 = 512 + t (t<64).
  const int row0 = t / VR_, v0 = t % VR_;            // row0 in [0,6)
  const int rrow0 = (row0 < 2) ? (rp * 2 + row0) : (sq * 4 + row0 - 2);
  const int idx0 = rid_to_vid[rrow0 * VR_ + v0];
  const F3 pa = *(const F3*)(((row0 < 2) ? v1s : v2s) + bN3 + (size_t)idx0 * 3);
  const bool have2 = (t < 64);                       // p1 = 512+t -> row 5
  F3 pb;
  const int v1 = 32 + t;                             // (512+t) - 5*96
  if (have2) {
    const int idx1 = rid_to_vid[(sq * 4 + 3) * VR_ + v1];
    pb = *(const F3*)(v2s + bN3 + (size_t)idx1 * 3);
  }

  // ---- overlap: mask layout detect + this wave's cell mask ----
  const int stride4 = detect_stride4(cm, lane);
  const bool active = stride4 ? (((const unsigned int*)cm)[cellIdx] != 0u)
                              : (cm[cellIdx] != 0);

  // ---- LDS SoA stores + single barrier ----
  __shared__ float s1[2][3 * VR_];
  __shared__ float s2[4][3 * VR_];
  {
    float* dst = (row0 < 2) ? s1[row0] : s2[row0 - 2];
    dst[v0] = pa.x; dst[VR_ + v0] = pa.y; dst[2 * VR_ + v0] = pa.z;
  }
  if (have2) {
    float* dst = s2[3];
    dst[v1] = pb.x; dst[VR_ + v1] = pb.y; dst[2 * VR_ + v1] = pb.z;
  }
  __syncthreads();

  if (!active) return;                      // wave-uniform, after the barrier

  const float* r1 = s1[w >> 2];
  const float* r2 = s2[w & 3];
  const int hi = lane >> 3, lo = lane & 7;  // 8x8 lane grid, 12x12 pair tile

  float Ax[12], Ay[12], Az[12];
  v2f Bx[6], By[6], Bz[6];
#pragma unroll
  for (int k = 0; k < 3; ++k) {
    *(float4*)&Ax[4 * k] = *(const float4*)(r1           + hi * 12 + 4 * k);
    *(float4*)&Ay[4 * k] = *(const float4*)(r1 +     VR_ + hi * 12 + 4 * k);
    *(float4*)&Az[4 * k] = *(const float4*)(r1 + 2 * VR_ + hi * 12 + 4 * k);
    *(float4*)&Bx[2 * k] = *(const float4*)(r2           + lo * 12 + 4 * k);
    *(float4*)&By[2 * k] = *(const float4*)(r2 +     VR_ + lo * 12 + 4 * k);
    *(float4*)&Bz[2 * k] = *(const float4*)(r2 + 2 * VR_ + lo * 12 + 4 * k);
  }

  float acc[4] = {3.4e38f, 3.4e38f, 3.4e38f, 3.4e38f};
#pragma unroll
  for (int i = 0; i < 12; ++i) {
    const v2f axx = {Ax[i], Ax[i]};
    const v2f ayy = {Ay[i], Ay[i]};
    const v2f azz = {Az[i], Az[i]};
#pragma unroll
    for (int j = 0; j < 6; ++j) {
      const v2f dx = axx - Bx[j];
      const v2f dy = ayy - By[j];
      const v2f dz = azz - Bz[j];
      const v2f d2 = dx * dx + dy * dy + dz * dz;
      acc[j & 3] = fminf(acc[j & 3], fminf(d2.x, d2.y));   // v_min3
    }
  }
  float mind2 = fminf(fminf(acc[0], acc[1]), fminf(acc[2], acc[3]));
#pragma unroll
  for (int off = 32; off > 0; off >>= 1)
    mind2 = fminf(mind2, __shfl_down(mind2, off, 64));
  if (lane == 0) minbuf[cellIdx] = sqrtf(fmaxf(mind2, 0.0f));
}

// ---------------------------------------------------------------------------
// Kernel 2: masked mean per batch (4 blocks). Per-wave layout detect. Reads
// only mask-true cells, so poisoned minbuf entries are never touched.
__global__ __launch_bounds__(256) void finalize_kernel(
    const float* __restrict__ min_d, const unsigned char* __restrict__ cm,
    float* __restrict__ out) {
  const int b = blockIdx.x;
  const int t = threadIdx.x;
  const int lane = t & 63;

  const int stride4 = detect_stride4(cm, lane);
  const unsigned int* cm32 = (const unsigned int*)cm;

  float sum = 0.0f, cnt = 0.0f;
  for (int i = t; i < R_ * R_; i += 256) {
    const int gi = b * R_ * R_ + i;
    const bool m = stride4 ? (cm32[gi] != 0u) : (cm[gi] != 0);
    if (m) { sum += min_d[gi]; cnt += 1.0f; }
  }
#pragma unroll
  for (int off = 32; off > 0; off >>= 1) {
    sum += __shfl_down(sum, off, 64);
    cnt += __shfl_down(cnt, off, 64);
  }
  __shared__ float ws_[4], wc_[4];
  if ((t & 63) == 0) { ws_[t >> 6] = sum; wc_[t >> 6] = cnt; }
  __syncthreads();
  if (t == 0) {
    out[b] = (ws_[0] + ws_[1] + ws_[2] + ws_[3]) /
             (wc_[0] + wc_[1] + wc_[2] + wc_[3]);
  }
}

// ---------------------------------------------------------------------------
extern "C" void kernel_launch(void* const* d_in, const int* in_sizes, int n_in,
                              void* d_out, int out_size, void* d_ws, size_t ws_size,
                              hipStream_t stream) {
  const float* v1s = (const float*)d_in[0];
  const float* v2s = (const float*)d_in[1];
  const unsigned char* cmaps = (const unsigned char*)d_in[2];
  const int* rid_to_vid = (const int*)d_in[3];
  float* out = (float*)d_out;
  float* minbuf = (float*)d_ws;            // 9216 floats = 36 KB

  const int N = in_sizes[0] / (B_ * 3);

  fused_cell_kernel<<<NBLK, 512, 0, stream>>>(
      v1s, v2s, rid_to_vid, cmaps, minbuf, N);
  finalize_kernel<<<B_, 256, 0, stream>>>(minbuf, cmaps, out);
}